// Round 1
// baseline (1844.657 us; speedup 1.0000x reference)
//
#include <hip/hip_runtime.h>
#include <math.h>

typedef __bf16 bf16_t;
typedef bf16_t bf16x8 __attribute__((ext_vector_type(8)));
typedef float f32x4 __attribute__((ext_vector_type(4)));

#define TOKS 73728
#define CCH 192

__device__ __forceinline__ float gelu_f(float x) {
  float t = tanhf(0.7978845608028654f*(x + 0.044715f*x*x*x));
  return 0.5f*x*(1.0f + t);
}

// ---------- weight prep: f32 [cnt][K][N] -> bf16 [cnt][N][K] ----------
__global__ void wprep_k(const float* __restrict__ in, bf16_t* __restrict__ out,
                        int K, int N, long total) {
  long idx = (long)blockIdx.x*256 + threadIdx.x;
  if (idx >= total) return;
  long kn = (long)K*N;
  long c = idx / kn;
  int rem = (int)(idx - c*kn);
  int k = rem / N, n = rem % N;
  out[c*kn + (long)n*K + k] = (bf16_t)in[idx];
}

// conv_w (192,192,3,3) f32 -> bf16 [tap][co][ci]
__global__ void cprep_k(const float* __restrict__ in, bf16_t* __restrict__ out) {
  int idx = blockIdx.x*256 + threadIdx.x;
  if (idx >= 9*192*192) return;
  int tap = idx / (192*192);
  int co = (idx / 192) % 192;
  int ci = idx % 192;
  out[idx] = (bf16_t)in[(co*192 + ci)*9 + tap];
}

// ---------- LayerNorm: f32 x (T,192) -> bf16 out ----------
__global__ __launch_bounds__(256) void ln_k(const float* __restrict__ x,
    const float* __restrict__ gg, const float* __restrict__ bb,
    bf16_t* __restrict__ out) {
  const int wid = blockIdx.x*4 + (threadIdx.x >> 6);
  const int l = threadIdx.x & 63;
  const float* row = x + (long)wid*CCH;
  float v0 = row[l], v1 = row[l+64], v2 = row[l+128];
  float s = v0+v1+v2, s2 = v0*v0+v1*v1+v2*v2;
  #pragma unroll
  for (int off=1; off<64; off<<=1) { s += __shfl_xor(s, off); s2 += __shfl_xor(s2, off); }
  float mu = s * (1.f/CCH);
  float rstd = rsqrtf(s2*(1.f/CCH) - mu*mu + 1e-5f);
  bf16_t* orow = out + (long)wid*CCH;
  orow[l]     = (bf16_t)((v0-mu)*rstd*gg[l]     + bb[l]);
  orow[l+64]  = (bf16_t)((v1-mu)*rstd*gg[l+64]  + bb[l+64]);
  orow[l+128] = (bf16_t)((v2-mu)*rstd*gg[l+128] + bb[l+128]);
}

// ---------- GEMM: C(M,N) = A(M,K) @ Bt(N,K)^T + bias ----------
// EPI 0: write bf16; 1: gelu -> bf16; 2: resid[row*192+col] += v
template<int EPI>
__global__ __launch_bounds__(256) void gemm_k(
    const bf16_t* __restrict__ A, int lda,
    const bf16_t* __restrict__ Bt,
    const float* __restrict__ bias,
    bf16_t* __restrict__ outb, int ldo, int ooff,
    float* __restrict__ resid,
    int N, int K) {
  __shared__ bf16_t Ah[64][40];
  __shared__ bf16_t Bh[64][40];
  const int tid = threadIdx.x;
  const int w = tid >> 6, l = tid & 63;
  const int srow = tid >> 2, sc = (tid & 3)*8;
  const long arow = (long)blockIdx.x*64 + srow;
  const int gn = blockIdx.y*64 + srow;
  f32x4 acc[4];
  #pragma unroll
  for (int i=0;i<4;++i) acc[i] = (f32x4){0.f,0.f,0.f,0.f};
  const bf16_t* ap = A + arow*lda + sc;
  const bf16_t* bp = Bt + (long)gn*K + sc;
  for (int kt=0; kt<K; kt+=32) {
    uint4 av = *(const uint4*)(ap + kt);
    uint4 bv = {0u,0u,0u,0u};
    if (gn < N) bv = *(const uint4*)(bp + kt);
    *(uint4*)(&Ah[srow][sc]) = av;
    *(uint4*)(&Bh[srow][sc]) = bv;
    __syncthreads();
    bf16x8 af = *(const bf16x8*)(&Ah[(w<<4) + (l&15)][(l>>4)*8]);
    #pragma unroll
    for (int ni=0; ni<4; ++ni) {
      bf16x8 bfr = *(const bf16x8*)(&Bh[(ni<<4) + (l&15)][(l>>4)*8]);
      acc[ni] = __builtin_amdgcn_mfma_f32_16x16x32_bf16(af, bfr, acc[ni], 0, 0, 0);
    }
    __syncthreads();
  }
  const long r0 = (long)blockIdx.x*64 + (w<<4) + ((l>>4)<<2);
  #pragma unroll
  for (int ni=0; ni<4; ++ni) {
    int col = blockIdx.y*64 + (ni<<4) + (l&15);
    if (col >= N) continue;
    float bsv = bias[col];
    #pragma unroll
    for (int e=0; e<4; ++e) {
      long row = r0 + e;
      float v = acc[ni][e] + bsv;
      if (EPI == 0)      outb[row*ldo + ooff + col] = (bf16_t)v;
      else if (EPI == 1) outb[row*ldo + ooff + col] = (bf16_t)gelu_f(v);
      else               resid[row*CCH + col] += v;
    }
  }
}

// ---------- window attention (1 block = 1 window, 1 wave = 1 head) ----------
__global__ __launch_bounds__(256) void win_attn_k(
    const bf16_t* __restrict__ qkv, bf16_t* __restrict__ aout,
    const float* __restrict__ rpb, int shift) {
  __shared__ float Ks[4][64][24];
  __shared__ float Vs[4][64][24];
  const int h = threadIdx.x >> 6, l = threadIdx.x & 63;
  const int wblk = blockIdx.x;
  const int b = wblk / 576, wi = wblk % 576;
  const int wh = wi / 24, ww = wi % 24;
  const int r = l >> 3, c = l & 7;
  const int hr = wh*8 + r, wr = ww*8 + c;
  int ho = hr + shift; if (ho >= 192) ho -= 192;
  int wo = wr + shift; if (wo >= 192) wo -= 192;
  const long tok = (long)b*36864 + (long)ho*192 + wo;
  const bf16_t* base = qkv + tok*576 + h*24;
  float q[24];
  #pragma unroll
  for (int j=0; j<3; ++j) {
    bf16x8 qv8 = *(const bf16x8*)(base + j*8);
    bf16x8 kv8 = *(const bf16x8*)(base + 96 + j*8);
    bf16x8 vv8 = *(const bf16x8*)(base + 192 + j*8);
    #pragma unroll
    for (int e=0; e<8; ++e) {
      q[j*8+e] = (float)qv8[e];
      Ks[h][l][j*8+e] = (float)kv8[e];
      Vs[h][l][j*8+e] = (float)vv8[e];
    }
  }
  __syncthreads();
  int qid = 0;
  if (shift) {
    int hid = (hr < 184) ? 0 : (hr < 188 ? 1 : 2);
    int wid2 = (wr < 184) ? 0 : (wr < 188 ? 1 : 2);
    qid = hid*3 + wid2;
  }
  const float scale = 0.20412414523193154f;
  float lg[64];
  #pragma unroll
  for (int m=0; m<64; ++m) {
    int r2 = m >> 3, c2 = m & 7;
    float dot = 0.f;
    #pragma unroll
    for (int d4=0; d4<6; ++d4) {
      float4 kv = *(const float4*)(&Ks[h][m][d4*4]);
      dot += q[d4*4+0]*kv.x + q[d4*4+1]*kv.y + q[d4*4+2]*kv.z + q[d4*4+3]*kv.w;
    }
    int ridx = (r - r2 + 7)*15 + (c - c2 + 7);
    float v = dot*scale + rpb[ridx*4 + h];
    if (shift) {
      int hr2 = wh*8 + r2, wr2 = ww*8 + c2;
      int hid2 = (hr2 < 184) ? 0 : (hr2 < 188 ? 1 : 2);
      int wid3 = (wr2 < 184) ? 0 : (wr2 < 188 ? 1 : 2);
      if (hid2*3 + wid3 != qid) v -= 100.f;
    }
    lg[m] = v;
  }
  float mx = -1e30f;
  #pragma unroll
  for (int m=0; m<64; ++m) mx = fmaxf(mx, lg[m]);
  float s = 0.f;
  float o[24];
  #pragma unroll
  for (int d=0; d<24; ++d) o[d] = 0.f;
  #pragma unroll
  for (int m=0; m<64; ++m) {
    float p = __expf(lg[m] - mx);
    s += p;
    #pragma unroll
    for (int d4=0; d4<6; ++d4) {
      float4 vv = *(const float4*)(&Vs[h][m][d4*4]);
      o[d4*4+0] += p*vv.x; o[d4*4+1] += p*vv.y; o[d4*4+2] += p*vv.z; o[d4*4+3] += p*vv.w;
    }
  }
  float inv = 1.f/s;
  bf16_t* ob = aout + tok*192 + h*24;
  #pragma unroll
  for (int j=0; j<3; ++j) {
    bf16x8 ov;
    #pragma unroll
    for (int e=0; e<8; ++e) ov[e] = (bf16_t)(o[j*8+e]*inv);
    *(bf16x8*)(ob + j*8) = ov;
  }
}

// ---------- anchored stripe attention ----------
__global__ __launch_bounds__(256) void stripe_attn_k(
    const bf16_t* __restrict__ qkv, const bf16_t* __restrict__ xn,
    bf16_t* __restrict__ aout) {
  __shared__ float Ks[4][64][24];
  __shared__ float Vs[4][64][24];
  __shared__ float An[4][16][24];
  __shared__ float Ts[4][16][24];
  const int h = threadIdx.x >> 6, l = threadIdx.x & 63;
  const int wblk = blockIdx.x;
  const int b = wblk / 576, wi = wblk % 576;
  const int wh = wi / 24, ww = wi % 24;
  const int r = l >> 3, c = l & 7;
  const long tok = (long)b*36864 + (long)(wh*8+r)*192 + (ww*8+c);
  const bf16_t* base = qkv + tok*576 + 288 + h*24;
  #pragma unroll
  for (int j=0; j<3; ++j) {
    bf16x8 kv8 = *(const bf16x8*)(base + 96 + j*8);
    bf16x8 vv8 = *(const bf16x8*)(base + 192 + j*8);
    #pragma unroll
    for (int e=0; e<8; ++e) {
      Ks[h][l][j*8+e] = (float)kv8[e];
      Vs[h][l][j*8+e] = (float)vv8[e];
    }
  }
  {
    int m = l >> 2, dq = l & 3;
    int ar = m >> 2, ac = m & 3;
    const long trow = (long)b*36864 + (long)(wh*8 + 2*ar)*192 + (ww*8 + 2*ac);
    #pragma unroll
    for (int j=0; j<6; ++j) {
      int d = dq*6 + j;
      float ssum = 0.f;
      ssum += (float)xn[trow*192       + 96 + h*24 + d];
      ssum += (float)xn[(trow+1)*192   + 96 + h*24 + d];
      ssum += (float)xn[(trow+192)*192 + 96 + h*24 + d];
      ssum += (float)xn[(trow+193)*192 + 96 + h*24 + d];
      An[h][m][d] = 0.25f*ssum;
    }
  }
  __syncthreads();
  const float scale = 0.20412414523193154f;
  {
    int g = l >> 2, qq = l & 3;
    float l2[16];
    #pragma unroll
    for (int t=0; t<16; ++t) {
      int k = qq*16 + t;
      float dot = 0.f;
      #pragma unroll
      for (int d4=0; d4<6; ++d4) {
        float4 av = *(const float4*)(&An[h][g][d4*4]);
        float4 kv = *(const float4*)(&Ks[h][k][d4*4]);
        dot += av.x*kv.x + av.y*kv.y + av.z*kv.z + av.w*kv.w;
      }
      l2[t] = dot*scale;
    }
    float mx = -1e30f;
    #pragma unroll
    for (int t=0; t<16; ++t) mx = fmaxf(mx, l2[t]);
    mx = fmaxf(mx, __shfl_xor(mx, 1));
    mx = fmaxf(mx, __shfl_xor(mx, 2));
    float ssum = 0.f;
    float p[16];
    #pragma unroll
    for (int t=0; t<16; ++t) { p[t] = __expf(l2[t]-mx); ssum += p[t]; }
    ssum += __shfl_xor(ssum, 1);
    ssum += __shfl_xor(ssum, 2);
    float ta[24];
    #pragma unroll
    for (int d=0; d<24; ++d) ta[d] = 0.f;
    #pragma unroll
    for (int t=0; t<16; ++t) {
      int k = qq*16 + t;
      #pragma unroll
      for (int d4=0; d4<6; ++d4) {
        float4 vv = *(const float4*)(&Vs[h][k][d4*4]);
        ta[d4*4+0] += p[t]*vv.x; ta[d4*4+1] += p[t]*vv.y;
        ta[d4*4+2] += p[t]*vv.z; ta[d4*4+3] += p[t]*vv.w;
      }
    }
    #pragma unroll
    for (int d=0; d<24; ++d) {
      ta[d] += __shfl_xor(ta[d], 1);
      ta[d] += __shfl_xor(ta[d], 2);
    }
    float inv = 1.f/ssum;
    #pragma unroll
    for (int j=0; j<6; ++j) Ts[h][g][qq*6+j] = ta[qq*6+j]*inv;
  }
  __syncthreads();
  {
    float qv[24];
    #pragma unroll
    for (int j=0; j<3; ++j) {
      bf16x8 q8 = *(const bf16x8*)(base + j*8);
      #pragma unroll
      for (int e=0; e<8; ++e) qv[j*8+e] = (float)q8[e];
    }
    float lg[16];
    #pragma unroll
    for (int m=0; m<16; ++m) {
      float dot = 0.f;
      #pragma unroll
      for (int d4=0; d4<6; ++d4) {
        float4 av = *(const float4*)(&An[h][m][d4*4]);
        dot += qv[d4*4+0]*av.x + qv[d4*4+1]*av.y + qv[d4*4+2]*av.z + qv[d4*4+3]*av.w;
      }
      lg[m] = dot*scale;
    }
    float mx = -1e30f;
    #pragma unroll
    for (int m=0; m<16; ++m) mx = fmaxf(mx, lg[m]);
    float s = 0.f;
    float o[24];
    #pragma unroll
    for (int d=0; d<24; ++d) o[d] = 0.f;
    #pragma unroll
    for (int m=0; m<16; ++m) {
      float p = __expf(lg[m]-mx);
      s += p;
      #pragma unroll
      for (int d4=0; d4<6; ++d4) {
        float4 tv = *(const float4*)(&Ts[h][m][d4*4]);
        o[d4*4+0] += p*tv.x; o[d4*4+1] += p*tv.y; o[d4*4+2] += p*tv.z; o[d4*4+3] += p*tv.w;
      }
    }
    float inv = 1.f/s;
    bf16_t* ob = aout + tok*192 + 96 + h*24;
    #pragma unroll
    for (int j=0; j<3; ++j) {
      bf16x8 ov;
      #pragma unroll
      for (int e=0; e<8; ++e) ov[e] = (bf16_t)(o[j*8+e]*inv);
      *(bf16x8*)(ob + j*8) = ov;
    }
  }
}

// ---------- 3x3 conv (implicit GEMM) + bias + res0 -> d_out ----------
__global__ __launch_bounds__(256) void conv_k(
    const float* __restrict__ x, const bf16_t* __restrict__ Wc,
    const float* __restrict__ cb, const float* __restrict__ res0,
    float* __restrict__ out) {
  __shared__ bf16_t Ah[64][40];
  __shared__ bf16_t Bh[64][40];
  const int tid = threadIdx.x;
  const int w = tid >> 6, l = tid & 63;
  const int srow = tid >> 2, sc = (tid & 3)*8;
  const long p0 = (long)blockIdx.x*64;
  const int bimg = (int)(p0 / 36864);
  const int rem = (int)(p0 % 36864);
  const int hh = rem / 192, w0 = rem % 192;
  f32x4 acc[4];
  #pragma unroll
  for (int i=0;i<4;++i) acc[i] = (f32x4){0.f,0.f,0.f,0.f};
  const int co = blockIdx.y*64 + srow;
  for (int tap=0; tap<9; ++tap) {
    const int dy = tap/3 - 1, dx = tap%3 - 1;
    const int hs = hh + dy;
    const int wsrc = w0 + srow + dx;
    const bool valid = (hs >= 0) && (hs < 192) && (wsrc >= 0) && (wsrc < 192);
    const float* src = x + (((long)bimg*36864 + (long)hs*192 + wsrc)*192 + sc);
    const bf16_t* bsrc = Wc + ((long)(tap*192 + co)*192 + sc);
    for (int kc=0; kc<192; kc+=32) {
      bf16x8 abv = {};
      if (valid) {
        float4 f0 = *(const float4*)(src + kc);
        float4 f1 = *(const float4*)(src + kc + 4);
        abv[0]=(bf16_t)f0.x; abv[1]=(bf16_t)f0.y; abv[2]=(bf16_t)f0.z; abv[3]=(bf16_t)f0.w;
        abv[4]=(bf16_t)f1.x; abv[5]=(bf16_t)f1.y; abv[6]=(bf16_t)f1.z; abv[7]=(bf16_t)f1.w;
      }
      *(bf16x8*)(&Ah[srow][sc]) = abv;
      *(uint4*)(&Bh[srow][sc]) = *(const uint4*)(bsrc + kc);
      __syncthreads();
      bf16x8 af = *(const bf16x8*)(&Ah[(w<<4)+(l&15)][(l>>4)*8]);
      #pragma unroll
      for (int ni=0; ni<4; ++ni) {
        bf16x8 bfr = *(const bf16x8*)(&Bh[(ni<<4)+(l&15)][(l>>4)*8]);
        acc[ni] = __builtin_amdgcn_mfma_f32_16x16x32_bf16(af, bfr, acc[ni], 0, 0, 0);
      }
      __syncthreads();
    }
  }
  const long r0 = p0 + (w<<4) + ((l>>4)<<2);
  #pragma unroll
  for (int ni=0; ni<4; ++ni) {
    int col = blockIdx.y*64 + (ni<<4) + (l&15);
    float cbv = cb[col];
    #pragma unroll
    for (int e=0; e<4; ++e) {
      long p = r0 + e;
      out[p*192 + col] = acc[ni][e] + cbv + res0[p*192 + col];
    }
  }
}

extern "C" void kernel_launch(void* const* d_in, const int* in_sizes, int n_in,
                              void* d_out, int out_size, void* d_ws, size_t ws_size,
                              hipStream_t stream) {
  const float* x_in     = (const float*)d_in[0];
  const float* norm1_g  = (const float*)d_in[1];
  const float* norm1_b  = (const float*)d_in[2];
  const float* qkv_w_w  = (const float*)d_in[3];
  const float* qkv_b_w  = (const float*)d_in[4];
  const float* qkv_w_s  = (const float*)d_in[5];
  const float* qkv_b_s  = (const float*)d_in[6];
  const float* proj_w   = (const float*)d_in[7];
  const float* proj_b   = (const float*)d_in[8];
  const float* rpb      = (const float*)d_in[9];
  const float* norm2_g  = (const float*)d_in[10];
  const float* norm2_b  = (const float*)d_in[11];
  const float* fc1_w    = (const float*)d_in[12];
  const float* fc1_b    = (const float*)d_in[13];
  const float* fc2_w    = (const float*)d_in[14];
  const float* fc2_b    = (const float*)d_in[15];
  const float* conv_w   = (const float*)d_in[16];
  const float* conv_b   = (const float*)d_in[17];

  char* ws = (char*)d_ws;
  float*  x_cur = (float*)ws;                         // 56,623,104 B
  bf16_t* xn    = (bf16_t*)(ws + 56623104);           // 28,311,552 B
  bf16_t* qh    = (bf16_t*)(ws + 84934656);           // 113,246,208 B
  bf16_t* aoutb = (bf16_t*)(ws + 198180864);          // 28,311,552 B
  bf16_t* WwinT = (bf16_t*)(ws + 226492416);
  bf16_t* WstrT  = WwinT  + 110592;
  bf16_t* WprojT = WstrT  + 110592;
  bf16_t* Wfc1T  = WprojT + 147456;
  bf16_t* Wfc2T  = Wfc1T  + 589824;
  bf16_t* WconvT = Wfc2T  + 589824;

  hipMemcpyAsync(x_cur, x_in, (size_t)TOKS*CCH*4, hipMemcpyDeviceToDevice, stream);

  wprep_k<<<(4*96*288 + 255)/256, 256, 0, stream>>>(qkv_w_w, WwinT, 96, 288, 4L*96*288);
  wprep_k<<<(4*96*288 + 255)/256, 256, 0, stream>>>(qkv_w_s, WstrT, 96, 288, 4L*96*288);
  wprep_k<<<(4*192*192 + 255)/256, 256, 0, stream>>>(proj_w, WprojT, 192, 192, 4L*192*192);
  wprep_k<<<(4*192*768 + 255)/256, 256, 0, stream>>>(fc1_w, Wfc1T, 192, 768, 4L*192*768);
  wprep_k<<<(4*768*192 + 255)/256, 256, 0, stream>>>(fc2_w, Wfc2T, 768, 192, 4L*768*192);
  cprep_k<<<(9*192*192 + 255)/256, 256, 0, stream>>>(conv_w, WconvT);

  const int MT = TOKS/64;  // 1152
  for (int i = 0; i < 4; ++i) {
    int shift = (i % 2 == 0) ? 4 : 0;
    ln_k<<<TOKS/4, 256, 0, stream>>>(x_cur, norm1_g + i*192, norm1_b + i*192, xn);
    dim3 g5(MT, 5), g3(MT, 3), g12(MT, 12);
    gemm_k<0><<<g5, 256, 0, stream>>>(xn,      192, WwinT + (long)i*96*288, qkv_b_w + i*288,
                                      qh, 576, 0,   nullptr, 288, 96);
    gemm_k<0><<<g5, 256, 0, stream>>>(xn + 96, 192, WstrT + (long)i*96*288, qkv_b_s + i*288,
                                      qh, 576, 288, nullptr, 288, 96);
    win_attn_k<<<1152, 256, 0, stream>>>(qh, aoutb, rpb + i*900, shift);
    stripe_attn_k<<<1152, 256, 0, stream>>>(qh, xn, aoutb);
    gemm_k<2><<<g3, 256, 0, stream>>>(aoutb, 192, WprojT + (long)i*192*192, proj_b + i*192,
                                      nullptr, 0, 0, x_cur, 192, 192);
    ln_k<<<TOKS/4, 256, 0, stream>>>(x_cur, norm2_g + i*192, norm2_b + i*192, xn);
    gemm_k<1><<<g12, 256, 0, stream>>>(xn, 192, Wfc1T + (long)i*192*768, fc1_b + i*768,
                                       qh, 768, 0, nullptr, 768, 192);
    gemm_k<2><<<g3, 256, 0, stream>>>(qh, 768, Wfc2T + (long)i*768*192, fc2_b + i*192,
                                      nullptr, 0, 0, x_cur, 192, 768);
  }
  dim3 gc(MT, 3);
  conv_k<<<gc, 256, 0, stream>>>(x_cur, WconvT, conv_b, x_in, (float*)d_out);
}